// Round 5
// baseline (255.936 us; speedup 1.0000x reference)
//
#include <hip/hip_runtime.h>
#include <stdint.h>

#define C_DIM  256
#define F_DIM  256
#define HW     4096   // 64*64
#define TW     128    // hw tile width per block
#define ETP    264    // et row pitch in bf16 (528 B = 33*16 B, odd # of 16B slots
                      //  -> even 8-lane/slot spread on both ds_write and ds_read)

typedef __attribute__((ext_vector_type(8))) short   bf16x8;
typedef __attribute__((ext_vector_type(4))) float   floatx4;

__device__ __forceinline__ unsigned short f32_to_bf16(float f) {
    union { float f; unsigned int u; } v; v.f = f;
    unsigned int u = v.u;
    return (unsigned short)((u + 0x7FFFu + ((u >> 16) & 1u)) >> 16);
}

// ---------------- prep: colsum + pack in one kernel, 16 blocks ----------------
// apack flat ((ftile*8 + kiter)*64 + lane)*8 + i holds
//   A[f = 16*ftile + (lane&15)][c = 32*kiter + (lane>>4)*8 + i]  (bf16)
__global__ void prep_kernel(const float* __restrict__ b,
                            unsigned short* __restrict__ apack) {
    __shared__ float part[16][17];
    __shared__ float inv_s[16];
    const int t     = threadIdx.x;
    const int ftile = blockIdx.x;
    const int f0    = ftile * 16;

    const int fl = t & 15;
    const int cg = t >> 4;
    float s = 0.f;
#pragma unroll
    for (int k = 0; k < 16; ++k) {
        float v = b[(cg + 16 * k) * F_DIM + f0 + fl];
        s += v * v;
    }
    part[cg][fl] = s;
    __syncthreads();
    if (t < 16) {
        float acc = 0.f;
#pragma unroll
        for (int g = 0; g < 16; ++g) acc += part[g][t];
        inv_s[t] = 1.0f / acc;
    }
    __syncthreads();

#pragma unroll
    for (int e = t; e < 512; e += 256) {
        const int kiter = e >> 6;
        const int lane  = e & 63;
        const int f     = f0 + (lane & 15);
        const int c0    = kiter * 32 + ((lane >> 4) << 3);
        const float inv = inv_s[lane & 15];
        bf16x8 v;
#pragma unroll
        for (int i = 0; i < 8; ++i) {
            float w = b[(c0 + i) * F_DIM + f];
            v[i] = (short)f32_to_bf16(w * w * inv);
        }
        *(bf16x8*)(apack + ((size_t)(ftile * 8 + kiter) * 64 + lane) * 8) = v;
    }
}

// ---------------- main fused kernel: TWO PHASES, ONE BARRIER ----------------
// out[b,f,hw] = log( sum_c exp(x[b,c,hw]) * p[c,f] )  (x ~ N(0,1): exp safe).
//
// Block = (batch, 128-wide hw tile), 512 threads = 8 waves, 2 blocks/CU
// (LDS 66 KiB). Theory: the old per-chunk barrier convoy + end-of-block write
// burst serialized the chip into read-storm/write-storm phases at ~2.4 TB/s
// (6 structural variants, rate invariant). This version removes ALL
// synchronization except one barrier:
//
// Phase 1 (no barriers): thread (j = t&127, cg = t>>7) loads its 64 x values
//   x[c = 32r + cg*8 + q][hw0 + j] directly to registers (per-wave segments of
//   256 B; compiler free to keep many loads in flight -- no convoy gating),
//   applies exp, packs bf16, one ds_write_b128 per round into the full-slice
//   transpose buffer et[j][c].
// __syncthreads()
// Phase 2 (no barriers, no waitcnts): wave wv computes f-tiles 2wv+rr
//   (rr=0,1) x all 128 hw x K=256 from et (16x reuse), then logs and stores
//   dwordx4 (every 64 B out line fully covered by a single instruction,
//   write-back path -- measured exact traffic). Waves drift and retire
//   independently -> reads and writes mix chip-wide instead of alternating.
__global__ __launch_bounds__(512, 4)
void mixture_kernel(const float* __restrict__ x,
                    const unsigned short* __restrict__ apack,
                    float* __restrict__ out) {
    __shared__ __align__(16) unsigned short et[TW][ETP];   // 66 KiB

    const int t     = threadIdx.x;
    const int wv    = t >> 6;        // 0..7
    const int lane  = t & 63;
    const int llo   = lane & 15;
    const int lhi   = lane >> 4;
    const int batch = blockIdx.x >> 5;
    const int hw0   = (blockIdx.x & 31) * TW;

    const int j  = t & 127;          // hw column this thread owns in phase 1
    const int cg = t >> 7;           // c-octet group (0..3)

    const float* xb = x + (size_t)batch * C_DIM * HW + hw0 + j;

    // ---- Phase 1: load -> exp -> transpose into et, 8 rounds of 32 c ----
    // Per round: 8 scalar global loads (independent across rounds; the
    // compiler software-pipelines them), 8 exp+cvt, 1 ds_write_b128.
#pragma unroll
    for (int r = 0; r < 8; ++r) {
        const int c0 = r * 32 + cg * 8;
        float xv[8];
#pragma unroll
        for (int q = 0; q < 8; ++q)
            xv[q] = xb[(size_t)(c0 + q) * HW];
        bf16x8 v;
#pragma unroll
        for (int q = 0; q < 8; ++q)
            v[q] = (short)f32_to_bf16(__expf(xv[q]));
        *(bf16x8*)&et[j][c0] = v;
    }

    __syncthreads();   // the only barrier in the kernel

    // ---- Phase 2: per wave, 2 rounds x (one 16-f tile over full K) ----
    const bf16x8* ap = (const bf16x8*)apack;
    float* obase = out + (size_t)batch * F_DIM * HW + hw0 + lhi * 4;

#pragma unroll
    for (int rr = 0; rr < 2; ++rr) {
        const int ft = wv * 2 + rr;          // f-tile 0..15

        bf16x8 af[8];
#pragma unroll
        for (int ks = 0; ks < 8; ++ks)
            af[ks] = ap[((size_t)ft * 8 + ks) * 64 + lane];

        floatx4 acc[8];
#pragma unroll
        for (int jt = 0; jt < 8; ++jt)
            acc[jt] = (floatx4){0.f, 0.f, 0.f, 0.f};

        // ks outer -> 8 independent acc chains per step (no MFMA dep stalls)
#pragma unroll
        for (int ks = 0; ks < 8; ++ks) {
#pragma unroll
            for (int jt = 0; jt < 8; ++jt) {
                bf16x8 bfrag =
                    *(const bf16x8*)&et[jt * 16 + llo][ks * 32 + lhi * 8];
                // swapped operands: D = E^T x P, lane holds
                // D[hw_local = lhi*4 + k4][f_local = llo]
                acc[jt] = __builtin_amdgcn_mfma_f32_16x16x32_bf16(
                    bfrag, af[ks], acc[jt], 0, 0, 0);
            }
        }

        // store: f = ft*16 + llo, hw = hw0 + jt*16 + lhi*4 + k4
        float* orow = obase + (size_t)(ft * 16 + llo) * HW;
#pragma unroll
        for (int jt = 0; jt < 8; ++jt) {
            floatx4 o;
#pragma unroll
            for (int k4 = 0; k4 < 4; ++k4) o[k4] = __logf(acc[jt][k4]);
            *(floatx4*)(orow + jt * 16) = o;
        }
    }
}

extern "C" void kernel_launch(void* const* d_in, const int* in_sizes, int n_in,
                              void* d_out, int out_size, void* d_ws, size_t ws_size,
                              hipStream_t stream) {
    const float* x      = (const float*)d_in[0];   // (32,256,64,64) f32
    const float* biases = (const float*)d_in[1];   // (1,1,256,256) f32
    float* out = (float*)d_out;                    // (32,256,64,64) f32

    unsigned short* apack = (unsigned short*)d_ws;  // 128 KiB

    prep_kernel<<<16, 256, 0, stream>>>(biases, apack);
    mixture_kernel<<<1024, 512, 0, stream>>>(x, apack, out);
}

// Round 6
// 242.571 us; speedup vs baseline: 1.0551x; 1.0551x over previous
//
#include <hip/hip_runtime.h>
#include <stdint.h>

#define C_DIM  256
#define F_DIM  256
#define HW     4096   // 64*64
#define TW     128    // hw tile width per block
#define NCHUNK 8      // K chunks of 32 c each
#define ETP    40     // et row pitch in bf16 (80 B = odd # of 16B blocks)

typedef __attribute__((ext_vector_type(8))) short   bf16x8;
typedef __attribute__((ext_vector_type(4))) float   floatx4;

__device__ __forceinline__ unsigned short f32_to_bf16(float f) {
    union { float f; unsigned int u; } v; v.f = f;
    unsigned int u = v.u;
    return (unsigned short)((u + 0x7FFFu + ((u >> 16) & 1u)) >> 16);
}

// async global->LDS, 16 B per lane (lds dst = wave-uniform base + lane*16)
__device__ __forceinline__ void async_load16(const float* g, float* l) {
    __builtin_amdgcn_global_load_lds(
        (const __attribute__((address_space(1))) void*)g,
        (__attribute__((address_space(3))) void*)l, 16, 0, 0);
}

// ---------------- prep: colsum + pack in one kernel, 16 blocks ----------------
// Block ftile handles f in [16*ftile, 16*ftile+16).
// apack flat ((ftile*8 + kiter)*64 + lane)*8 + i holds
//   A[f = 16*ftile + (lane&15)][c = 32*kiter + (lane>>4)*8 + i]  (bf16)
__global__ void prep_kernel(const float* __restrict__ b,
                            unsigned short* __restrict__ apack) {
    __shared__ float part[16][17];
    __shared__ float inv_s[16];
    const int t     = threadIdx.x;
    const int ftile = blockIdx.x;
    const int f0    = ftile * 16;

    const int fl = t & 15;
    const int cg = t >> 4;
    float s = 0.f;
#pragma unroll
    for (int k = 0; k < 16; ++k) {
        float v = b[(cg + 16 * k) * F_DIM + f0 + fl];
        s += v * v;
    }
    part[cg][fl] = s;
    __syncthreads();
    if (t < 16) {
        float acc = 0.f;
#pragma unroll
        for (int g = 0; g < 16; ++g) acc += part[g][t];
        inv_s[t] = 1.0f / acc;
    }
    __syncthreads();

#pragma unroll
    for (int e = t; e < 512; e += 256) {
        const int kiter = e >> 6;
        const int lane  = e & 63;
        const int f     = f0 + (lane & 15);
        const int c0    = kiter * 32 + ((lane >> 4) << 3);
        const float inv = inv_s[lane & 15];
        bf16x8 v;
#pragma unroll
        for (int i = 0; i < 8; ++i) {
            float w = b[(c0 + i) * F_DIM + f];
            v[i] = (short)f32_to_bf16(w * w * inv);
        }
        *(bf16x8*)(apack + ((size_t)(ftile * 8 + kiter) * 64 + lane) * 8) = v;
    }
}

// ---------------- main fused kernel ----------------
// out[b,f,hw] = log( sum_c exp(x[b,c,hw]) * p[c,f] )  (x ~ N(0,1): exp safe,
// all-positive sum -> no max subtraction needed).
//
// Block = (batch, 128-wide hw tile), 512 threads = 8 waves, 2 blocks/CU.
//
// FINAL (reverted to verified-best R1 structure, 84 us):
// ONE barrier per K-chunk, sbuf 3-deep, DMA 2 chunks ahead, counted vmcnt.
// Session evidence (7 structural variants, R0-R5): dur pinned at 84-97 us
// with fabric rate 2.1-2.6 TB/s, exact-minimal traffic, and ALL pipes <33%
// busy regardless of barrier count, pipeline depth, store width, L2/L3
// bypass, tile shape, or removing LDS/sync entirely. Consistent with a
// per-CU outstanding-miss capacity (~4-5 KB in flight) x ~700 cy mixed
// L3/HBM latency => ~12 GB/s/CU => ~2.5 TB/s chip-wide ceiling for this
// read+write mixed pattern. This structure sits on that ceiling.
__global__ __launch_bounds__(512, 4)
void mixture_kernel(const float* __restrict__ x,
                    const unsigned short* __restrict__ apack,
                    float* __restrict__ out) {
    __shared__ __align__(16) float          sbuf[3][32][TW];   // 48 KiB
    __shared__ __align__(16) unsigned short et[2][TW][ETP];    // 20 KiB

    const int t     = threadIdx.x;
    const int wv    = t >> 6;        // 0..7
    const int lane  = t & 63;
    const int batch = blockIdx.x >> 5;
    const int hw0   = (blockIdx.x & 31) * TW;

    const float* xb = x + (size_t)batch * C_DIM * HW + hw0;

    // ---- DMA one chunk: wave wv loads rows 4wv..4wv+3; 2 rows per instr ----
    // (lanes 0-31 -> row rr, lanes 32-63 -> row rr+1; 1 KiB contiguous LDS)
#define DMA_CHUNK(ck, buf)                                                      \
    {                                                                           \
        _Pragma("unroll")                                                       \
        for (int r = 0; r < 2; ++r) {                                           \
            const int rr = 4 * wv + 2 * r;                                      \
            const float* g = xb + (size_t)((ck) * 32 + rr + (lane >> 5)) * HW   \
                                + (lane & 31) * 4;                              \
            async_load16(g, &sbuf[buf][rr][0]);                                 \
        }                                                                       \
    }

    // ---- transpose one chunk: sbuf[sb][c][j] -> exp -> bf16 -> et[eb][j][c] ----
#define TRANSPOSE_CHUNK(sb, eb)                                                 \
    {                                                                           \
        float xv[8];                                                            \
        _Pragma("unroll")                                                       \
        for (int q = 0; q < 8; ++q) xv[q] = sbuf[sb][cg * 8 + q][j];            \
        bf16x8 v;                                                               \
        _Pragma("unroll")                                                       \
        for (int q = 0; q < 8; ++q) v[q] = (short)f32_to_bf16(__expf(xv[q]));   \
        *(bf16x8*)&et[eb][j][cg * 8] = v;                                       \
    }

    const int llo = lane & 15;
    const int lhi = lane >> 4;
    const int j   = t & 127;   // hw column for transpose
    const int cg  = t >> 7;    // c-octet group for transpose

    floatx4 acc[2][8];
#pragma unroll
    for (int a = 0; a < 2; ++a)
#pragma unroll
        for (int jt = 0; jt < 8; ++jt)
            acc[a][jt] = (floatx4){0.f, 0.f, 0.f, 0.f};

    const bf16x8* ap = (const bf16x8*)apack;

    // ---- prologue: fill pipeline 2 deep, transpose chunk 0 ----
    DMA_CHUNK(0, 0);
    asm volatile("" ::: "memory");   // pin afrag(0) loads after DMA(0) issue
    bf16x8 a0c = ap[((2 * wv + 0) * 8 + 0) * 64 + lane];
    bf16x8 a1c = ap[((2 * wv + 1) * 8 + 0) * 64 + lane];
    DMA_CHUNK(1, 1);
    // drain DMA(0) (4 younger vmem allowed: afrag(0) + DMA(1), any order)
    asm volatile("s_waitcnt vmcnt(4)\n\ts_barrier" ::: "memory");
    TRANSPOSE_CHUNK(0, 0);

#pragma unroll
    for (int i = 0; i < NCHUNK; ++i) {
        const int eb = i & 1;

        // afrag loads for chunk i+1 (consumed next interval)
        bf16x8 a0n, a1n;
        if (i < NCHUNK - 1) {
            a0n = ap[((2 * wv + 0) * 8 + (i + 1)) * 64 + lane];
            a1n = ap[((2 * wv + 1) * 8 + (i + 1)) * 64 + lane];
        }
        // DMA chunk i+2 (needed at barrier i+1 -> ~2 compute phases in flight)
        if (i < NCHUNK - 2) DMA_CHUNK(i + 2, (i + 2) % 3);

        // single barrier per chunk: drain DMA(i+1)+afrag(i) (vmem) and all
        // prior-interval LDS ops; leave this interval's 4 vmem ops in flight
        if (i < NCHUNK - 2)
            asm volatile("s_waitcnt vmcnt(4) lgkmcnt(0)\n\ts_barrier" ::: "memory");
        else if (i == NCHUNK - 2)
            asm volatile("s_waitcnt vmcnt(2) lgkmcnt(0)\n\ts_barrier" ::: "memory");
        else
            asm volatile("s_waitcnt vmcnt(0) lgkmcnt(0)\n\ts_barrier" ::: "memory");

        // ---- MFMA chunk i (et[eb]) -- interleaves with transpose below ----
#pragma unroll
        for (int jt = 0; jt < 8; ++jt) {
            bf16x8 bfrag = *(const bf16x8*)&et[eb][jt * 16 + llo][lhi * 8];
            acc[0][jt] = __builtin_amdgcn_mfma_f32_16x16x32_bf16(
                a0c, bfrag, acc[0][jt], 0, 0, 0);
            acc[1][jt] = __builtin_amdgcn_mfma_f32_16x16x32_bf16(
                a1c, bfrag, acc[1][jt], 0, 0, 0);
        }

        // ---- transpose chunk i+1 into the other et buffer (VALU/LDS pipes,
        //      overlaps the MFMA above; hazards resolved at next barrier) ----
        if (i < NCHUNK - 1) TRANSPOSE_CHUNK((i + 1) % 3, eb ^ 1);

        if (i < NCHUNK - 1) { a0c = a0n; a1c = a1n; }
    }

    // ---- Epilogue: out[batch, f, hw0 + n] = log(acc) ----
    float* ob = out + (size_t)batch * F_DIM * HW + hw0;
#pragma unroll
    for (int a = 0; a < 2; ++a) {
        const int fbase = 32 * wv + 16 * a + lhi * 4;
#pragma unroll
        for (int r = 0; r < 4; ++r) {
            float* orow = ob + (size_t)(fbase + r) * HW;
#pragma unroll
            for (int jt = 0; jt < 8; ++jt)
                orow[jt * 16 + llo] = __logf(acc[a][jt][r]);
        }
    }
}

extern "C" void kernel_launch(void* const* d_in, const int* in_sizes, int n_in,
                              void* d_out, int out_size, void* d_ws, size_t ws_size,
                              hipStream_t stream) {
    const float* x      = (const float*)d_in[0];   // (32,256,64,64) f32
    const float* biases = (const float*)d_in[1];   // (1,1,256,256) f32
    float* out = (float*)d_out;                    // (32,256,64,64) f32

    unsigned short* apack = (unsigned short*)d_ws;  // 128 KiB

    prep_kernel<<<16, 256, 0, stream>>>(biases, apack);
    mixture_kernel<<<1024, 512, 0, stream>>>(x, apack, out);
}